// Round 1
// baseline (123.067 us; speedup 1.0000x reference)
//
#include <hip/hip_runtime.h>
#include <hip/hip_bf16.h>
#include <stdint.h>

// B=4, C=64, N=16384, K=16, CO=64 (fp32 I/O, int32 idx)
// 3 dispatches (R14 structure).
//  k1 gemm (MFMA): A=[W1+W2; W2] (128x64 bf16) @ x-tile -> y1p/y2p bf16-pairs (unchanged)
//  k2 gather: dwordx2 gathers (4 rows/inst, 16-lane row groups), SADDR 32-bit offsets,
//             max3-fused extremes, striped statsN atomicAdd
//  k3 out: reduce statsN -> scale/bias, affine+leaky+transpose, dwordx2 hselp loads
#define NDIM 16384
#define KNB 16
#define BNK_F 1048576.0f

typedef __attribute__((ext_vector_type(8))) short bf16x8_t;
typedef __attribute__((ext_vector_type(4))) float f32x4_t;

__device__ inline unsigned pack_bf16(float a, float b) {
    return (unsigned)__bfloat16_as_ushort(__float2bfloat16(a))
         | ((unsigned)__bfloat16_as_ushort(__float2bfloat16(b)) << 16);
}

// ---------------- Kernel 1: MFMA GEMM (R13/R14-proven, unchanged) ----------------
__global__ __launch_bounds__(256) void gemm_mfma_kernel(
    const float* __restrict__ x,            // (B, 64, N)
    const float* __restrict__ W,            // (64, 128)
    unsigned* __restrict__ y1p,             // (B,N,32) bf16-pairs
    unsigned* __restrict__ y2p,             // (B,N,32) bf16-pairs
    float* __restrict__ statsN)             // (32,128) striped stats - zeroed here
{
    __shared__ alignas(16) short lds_a[128 * 72];  // row pad 72 -> 2-way-free b128
    __shared__ alignas(16) short lds_b[64 * 72];   // x tile, n-major

    const int tid = threadIdx.x;
    if (blockIdx.x == 0) {
        for (int i = tid; i < 4096; i += 256) statsN[i] = 0.0f;
    }
    const int b  = blockIdx.x >> 8;
    const int n0 = (blockIdx.x & 255) << 6;

    // stage A (bf16): ch<64: w1+w2 ; ch>=64: w2
    for (int i = tid; i < 8192; i += 256) {
        int ch = i >> 6, c = i & 63;
        float a = (ch < 64) ? (W[ch * 128 + c] + W[ch * 128 + 64 + c])
                            : W[(ch - 64) * 128 + 64 + c];
        lds_a[ch * 72 + c] = (short)__bfloat16_as_ushort(__float2bfloat16(a));
    }
    // stage B: x (c-major fp32) -> lds_b[n][c] bf16, packed-pair writes
    {
        const float* xb = x + (size_t)b * 64 * NDIM + n0;
        const int n = tid & 63;
        unsigned* lb32 = (unsigned*)lds_b;
        for (int cp = tid >> 6; cp < 32; cp += 4) {
            int c = cp * 2;
            float x0 = xb[(size_t)c * NDIM + n];
            float x1 = xb[(size_t)(c + 1) * NDIM + n];
            lb32[n * 36 + cp] = pack_bf16(x0, x1);
        }
    }
    __syncthreads();

    const int lane = tid & 63;
    const int w    = tid >> 6;
    const int m    = lane & 15;              // A-row (ch) AND B-col (n) lane index
    const int q    = lane >> 4;              // k-octet / D-row quad
    const int n    = w * 16 + m;

    const bf16x8_t b0 = *(const bf16x8_t*)&lds_b[n * 72 + q * 8];        // k 0..31
    const bf16x8_t b1 = *(const bf16x8_t*)&lds_b[n * 72 + q * 8 + 32];   // k 32..63

    const size_t rowbase = ((size_t)(b * NDIM + n0 + n)) * 32;
    #pragma unroll
    for (int t = 0; t < 8; ++t) {
        const short* ap = &lds_a[(t * 16 + m) * 72 + q * 8];
        bf16x8_t a0 = *(const bf16x8_t*)ap;
        bf16x8_t a1 = *(const bf16x8_t*)(ap + 32);
        f32x4_t acc = {0.f, 0.f, 0.f, 0.f};
        acc = __builtin_amdgcn_mfma_f32_16x16x32_bf16(a0, b0, acc, 0, 0, 0);
        acc = __builtin_amdgcn_mfma_f32_16x16x32_bf16(a1, b1, acc, 0, 0, 0);
        // D: row(ch-in-tile)=q*4+r, col(n)=lane&15 -> 4 consecutive ch = 2 pairs
        unsigned* dst = (t < 4) ? y1p : y2p;
        uint2 pk = { pack_bf16(acc[0], acc[1]), pack_bf16(acc[2], acc[3]) };
        *(uint2*)&dst[rowbase + (t & 3) * 8 + q * 2] = pk;
    }
}

// ---------------- Kernel 2: gather, dwordx2 / 4-rows-per-instruction ----------------
// 2048 blocks x 256, XCD-pinned batches. Per wave: 8 rows, 2 groups of 4 rows.
// Each gather inst: 16-lane row groups, 8 B/lane -> 4x128B requests (same MLP as
// before in requests, half the VMEM instructions).
__global__ __launch_bounds__(256, 4) void gather_kernel(
    const unsigned* __restrict__ y1p,        // (B,N,32) bf16-pairs
    const unsigned* __restrict__ y2p,
    const int* __restrict__ ei,              // (B, N, 16)
    const float* __restrict__ gamma,
    unsigned* __restrict__ hselp,            // (B,N,32) bf16-pairs
    float* __restrict__ statsN)              // (32,128)
{
    const int tid  = threadIdx.x;
    const int w    = __builtin_amdgcn_readfirstlane(tid >> 6);
    const int lane = tid & 63;
    const int r4   = lane >> 4;              // row-in-quad 0..3
    const int c4   = lane & 15;              // owns pairs 2c4,2c4+1 = channels 4c4..4c4+3
    const int g    = blockIdx.x;
    const int xcd  = g & 7;
    const int b    = xcd >> 1;
    const int row0 = b * NDIM + (xcd & 1) * 8192 + (g >> 3) * 32 + w * 8;

    const f32x4_t gv = *(const f32x4_t*)&gamma[c4 * 4];
    unsigned sgn[4];
    #pragma unroll
    for (int j = 0; j < 4; ++j) sgn[j] = (gv[j] >= 0.0f) ? 0x80000000u : 0u;

    // uniform 64-bit base + per-lane unsigned 32-bit byte offset -> SADDR loads
    const char* y2base = (const char*)(y2p + (size_t)b * NDIM * 32);
    const unsigned coff = (unsigned)(c4 << 3);
    const int* ib = ei + (size_t)row0 * KNB;     // 128 contiguous ints, wave-uniform

    // y1 loads issued before the gather bursts (stay in flight under them)
    const uint2 y1a = *(const uint2*)&y1p[(size_t)(row0 + r4) * 32 + c4 * 2];
    const uint2 y1b = *(const uint2*)&y1p[(size_t)(row0 + 4 + r4) * 32 + c4 * 2];

    float ss[4] = {0.f, 0.f, 0.f, 0.f};
    float qq[4] = {0.f, 0.f, 0.f, 0.f};

    #pragma unroll
    for (int grp = 0; grp < 2; ++grp) {
        const int* ig = ib + grp * 64;
        uint2 u[16];
        #pragma unroll
        for (int k = 0; k < KNB; ++k) {
            int j = (r4 & 2) ? ((r4 & 1) ? ig[48 + k] : ig[32 + k])
                             : ((r4 & 1) ? ig[16 + k] : ig[k]);
            u[k] = *(const uint2*)(y2base + (((unsigned)j << 7) + coff));
        }

        float s[4] = {0.f, 0.f, 0.f, 0.f};
        float q[4] = {0.f, 0.f, 0.f, 0.f};
        float M[4] = {-3.402823e38f, -3.402823e38f, -3.402823e38f, -3.402823e38f};
        #pragma unroll
        for (int k = 0; k < KNB; k += 2) {
            float va[4], vb[4];
            va[0] = __uint_as_float(u[k].x << 16);
            va[1] = __uint_as_float(u[k].x & 0xffff0000u);
            va[2] = __uint_as_float(u[k].y << 16);
            va[3] = __uint_as_float(u[k].y & 0xffff0000u);
            vb[0] = __uint_as_float(u[k + 1].x << 16);
            vb[1] = __uint_as_float(u[k + 1].x & 0xffff0000u);
            vb[2] = __uint_as_float(u[k + 1].y << 16);
            vb[3] = __uint_as_float(u[k + 1].y & 0xffff0000u);
            #pragma unroll
            for (int j = 0; j < 4; ++j) {
                s[j] += va[j];
                s[j] += vb[j];
                q[j] = fmaf(va[j], va[j], q[j]);
                q[j] = fmaf(vb[j], vb[j], q[j]);
                // nested fmax -> v_max3_f32
                M[j] = fmaxf(fmaxf(M[j], __uint_as_float(__float_as_uint(va[j]) ^ sgn[j])),
                             __uint_as_float(__float_as_uint(vb[j]) ^ sgn[j]));
            }
        }

        const uint2 y1u = grp ? y1b : y1a;
        float y1v[4];
        y1v[0] = __uint_as_float(y1u.x << 16);
        y1v[1] = __uint_as_float(y1u.x & 0xffff0000u);
        y1v[2] = __uint_as_float(y1u.y << 16);
        y1v[3] = __uint_as_float(y1u.y & 0xffff0000u);

        float h[4];
        #pragma unroll
        for (int j = 0; j < 4; ++j) {
            h[j] = y1v[j] - __uint_as_float(__float_as_uint(M[j]) ^ sgn[j]);
            ss[j] += 16.f * y1v[j] - s[j];
            qq[j] += fmaf(fmaf(-2.f, s[j], 16.f * y1v[j]), y1v[j], q[j]);
        }
        uint2 ho;
        ho.x = pack_bf16(h[0], h[1]);
        ho.y = pack_bf16(h[2], h[3]);
        *(uint2*)&hselp[(size_t)(row0 + grp * 4 + r4) * 32 + c4 * 2] = ho;
    }

    // reduce over the 4 row-quads (lanes ^16, ^32)
    #pragma unroll
    for (int j = 0; j < 4; ++j) {
        ss[j] += __shfl_xor(ss[j], 16);
        ss[j] += __shfl_xor(ss[j], 32);
        qq[j] += __shfl_xor(qq[j], 16);
        qq[j] += __shfl_xor(qq[j], 32);
    }

    __shared__ float rs[4][64];
    __shared__ float rq[4][64];
    if (r4 == 0) {
        #pragma unroll
        for (int j = 0; j < 4; ++j) {
            rs[w][c4 * 4 + j] = ss[j];
            rq[w][c4 * 4 + j] = qq[j];
        }
    }
    __syncthreads();
    if (tid < 128) {
        const int c = tid & 63;
        float v = 0.f;
        if (tid < 64) { for (int r = 0; r < 4; ++r) v += rs[r][c]; }
        else          { for (int r = 0; r < 4; ++r) v += rq[r][c]; }
        atomicAdd(&statsN[(g & 31) * 128 + tid], v);   // striped: ~64 adds/line
    }
}

// ---------------- Kernel 3: reduce-in-prologue + affine + leaky + transpose ----------------
__global__ __launch_bounds__(256) void out_kernel(
    const unsigned* __restrict__ hselp,      // (B,N,32) bf16-pairs
    const float* __restrict__ statsN,        // (32,128)
    const float* __restrict__ gamma,
    const float* __restrict__ beta,
    float* __restrict__ out)                 // (B, 64, N)
{
    __shared__ float tile[64 * 65];
    __shared__ float colsum[128];
    __shared__ float sc[64], bi[64];
    const int tid = threadIdx.x;

    if (tid < 128) {
        float v = 0.f;
        #pragma unroll
        for (int i = 0; i < 32; ++i) v += statsN[i * 128 + tid];
        colsum[tid] = v;
    }
    __syncthreads();
    if (tid < 64) {
        float mean = colsum[tid] * (1.0f / BNK_F);
        float var  = colsum[64 + tid] * (1.0f / BNK_F) - mean * mean;
        float s    = gamma[tid] * rsqrtf(var + 1e-5f);
        sc[tid] = s;
        bi[tid] = beta[tid] - mean * s;
    }
    __syncthreads();

    const int b  = blockIdx.x >> 8;
    const int n0 = (blockIdx.x & 255) << 6;
    const size_t bn0 = (size_t)b * NDIM + n0;
    const int c4 = tid & 15;

    for (int r = tid >> 4; r < 64; r += 16) {
        uint2 u = *(const uint2*)&hselp[(bn0 + r) * 32 + c4 * 2];
        float v0 = fmaf(sc[4 * c4],     __uint_as_float(u.x << 16),         bi[4 * c4]);
        float v1 = fmaf(sc[4 * c4 + 1], __uint_as_float(u.x & 0xffff0000u), bi[4 * c4 + 1]);
        float v2 = fmaf(sc[4 * c4 + 2], __uint_as_float(u.y << 16),         bi[4 * c4 + 2]);
        float v3 = fmaf(sc[4 * c4 + 3], __uint_as_float(u.y & 0xffff0000u), bi[4 * c4 + 3]);
        v0 = (v0 >= 0.f) ? v0 : 0.2f * v0;
        v1 = (v1 >= 0.f) ? v1 : 0.2f * v1;
        v2 = (v2 >= 0.f) ? v2 : 0.2f * v2;
        v3 = (v3 >= 0.f) ? v3 : 0.2f * v3;
        tile[r * 65 + 4 * c4]     = v0;
        tile[r * 65 + 4 * c4 + 1] = v1;
        tile[r * 65 + 4 * c4 + 2] = v2;
        tile[r * 65 + 4 * c4 + 3] = v3;
    }
    __syncthreads();
    const int lane = tid & 63;
    for (int o = tid >> 6; o < 64; o += 4)
        out[((size_t)(b * 64 + o) << 14) + n0 + lane] = tile[lane * 65 + o];
}

extern "C" void kernel_launch(void* const* d_in, const int* in_sizes, int n_in,
                              void* d_out, int out_size, void* d_ws, size_t ws_size,
                              hipStream_t stream) {
    const float* x     = (const float*)d_in[0];
    const int*   ei    = (const int*)d_in[1];
    const float* W     = (const float*)d_in[2];
    const float* gamma = (const float*)d_in[3];
    const float* beta  = (const float*)d_in[4];
    float* out = (float*)d_out;

    char* ws = (char*)d_ws;
    unsigned* y1p    = (unsigned*)(ws);                       // 8 MiB (bf16 pairs)
    unsigned* y2p    = (unsigned*)(ws + 8388608);             // 8 MiB
    unsigned* hselp  = (unsigned*)(ws + 16777216);            // 8 MiB
    float*    statsN = (float*)(ws + 25165824);               // 16 KiB (32x128)

    gemm_mfma_kernel <<<dim3(1024), dim3(256), 0, stream>>>(x, W, y1p, y2p, statsN);
    gather_kernel    <<<dim3(2048), dim3(256), 0, stream>>>(y1p, y2p, ei, gamma, hselp, statsN);
    out_kernel       <<<dim3(1024), dim3(256), 0, stream>>>(hselp, statsN, gamma, beta, out);
}

// Round 2
// 105.847 us; speedup vs baseline: 1.1627x; 1.1627x over previous
//
#include <hip/hip_runtime.h>
#include <hip/hip_bf16.h>
#include <stdint.h>

// B=4, C=64, N=16384, K=16, CO=64 (fp32 I/O, int32 idx)
// R2 = R0-proven structure + register-neutral instruction cuts:
//  k1 gemm (MFMA): A-staging via float4 W loads (4x fewer staging instrs)
//  k2 gather: R0's 2-interleaved-row-pairs (untouched loads), max3-paired extremes
//  k3 out: dwordx2 hselp loads (16 lanes/row)
#define NDIM 16384
#define KNB 16
#define BNK_F 1048576.0f

typedef __attribute__((ext_vector_type(8))) short bf16x8_t;
typedef __attribute__((ext_vector_type(4))) float f32x4_t;

__device__ inline unsigned pack_bf16(float a, float b) {
    return (unsigned)__bfloat16_as_ushort(__float2bfloat16(a))
         | ((unsigned)__bfloat16_as_ushort(__float2bfloat16(b)) << 16);
}

// ---------------- Kernel 1: MFMA GEMM ----------------
__global__ __launch_bounds__(256) void gemm_mfma_kernel(
    const float* __restrict__ x,            // (B, 64, N)
    const float* __restrict__ W,            // (64, 128)
    unsigned* __restrict__ y1p,             // (B,N,32) bf16-pairs
    unsigned* __restrict__ y2p,             // (B,N,32) bf16-pairs
    float* __restrict__ statsN)             // (32,128) striped stats - zeroed here
{
    __shared__ alignas(16) short lds_a[128 * 72];  // row pad 72 -> 2-way-free b128
    __shared__ alignas(16) short lds_b[64 * 72];   // x tile, n-major

    const int tid = threadIdx.x;
    if (blockIdx.x == 0) {
        for (int i = tid; i < 4096; i += 256) statsN[i] = 0.0f;
    }
    const int b  = blockIdx.x >> 8;
    const int n0 = (blockIdx.x & 255) << 6;

    // stage A (bf16) via float4: 1024 (row r, float4-col q) pairs.
    // ch=r:    W1+W2 = W[r][4q+j] + W[r][64+4q+j]
    // ch=64+r: W2    = W[r][64+4q+j]
    for (int idx = tid; idx < 1024; idx += 256) {
        const int r = idx >> 4, q = idx & 15;
        const f32x4_t wa = *(const f32x4_t*)&W[r * 128 + q * 4];
        const f32x4_t wb = *(const f32x4_t*)&W[r * 128 + 64 + q * 4];
        uint2 pa = { pack_bf16(wa[0] + wb[0], wa[1] + wb[1]),
                     pack_bf16(wa[2] + wb[2], wa[3] + wb[3]) };
        uint2 pb = { pack_bf16(wb[0], wb[1]), pack_bf16(wb[2], wb[3]) };
        *(uint2*)&lds_a[r * 72 + q * 4]        = pa;   // byte off r*144+q*8: 8B aligned
        *(uint2*)&lds_a[(64 + r) * 72 + q * 4] = pb;
    }
    // stage B: x (c-major fp32) -> lds_b[n][c] bf16, packed-pair writes
    {
        const float* xb = x + (size_t)b * 64 * NDIM + n0;
        const int n = tid & 63;
        unsigned* lb32 = (unsigned*)lds_b;
        for (int cp = tid >> 6; cp < 32; cp += 4) {
            int c = cp * 2;
            float x0 = xb[(size_t)c * NDIM + n];
            float x1 = xb[(size_t)(c + 1) * NDIM + n];
            lb32[n * 36 + cp] = pack_bf16(x0, x1);
        }
    }
    __syncthreads();

    const int lane = tid & 63;
    const int w    = tid >> 6;
    const int m    = lane & 15;              // A-row (ch) AND B-col (n) lane index
    const int q    = lane >> 4;              // k-octet / D-row quad
    const int n    = w * 16 + m;

    const bf16x8_t b0 = *(const bf16x8_t*)&lds_b[n * 72 + q * 8];        // k 0..31
    const bf16x8_t b1 = *(const bf16x8_t*)&lds_b[n * 72 + q * 8 + 32];   // k 32..63

    const size_t rowbase = ((size_t)(b * NDIM + n0 + n)) * 32;
    #pragma unroll
    for (int t = 0; t < 8; ++t) {
        const short* ap = &lds_a[(t * 16 + m) * 72 + q * 8];
        bf16x8_t a0 = *(const bf16x8_t*)ap;
        bf16x8_t a1 = *(const bf16x8_t*)(ap + 32);
        f32x4_t acc = {0.f, 0.f, 0.f, 0.f};
        acc = __builtin_amdgcn_mfma_f32_16x16x32_bf16(a0, b0, acc, 0, 0, 0);
        acc = __builtin_amdgcn_mfma_f32_16x16x32_bf16(a1, b1, acc, 0, 0, 0);
        // D: row(ch-in-tile)=q*4+r, col(n)=lane&15 -> 4 consecutive ch = 2 pairs
        unsigned* dst = (t < 4) ? y1p : y2p;
        uint2 pk = { pack_bf16(acc[0], acc[1]), pack_bf16(acc[2], acc[3]) };
        *(uint2*)&dst[rowbase + (t & 3) * 8 + q * 2] = pk;
    }
}

// ---------------- Kernel 2: gather, 2 interleaved row-pairs (R0 loads) ----------------
// 2048 blocks x 256, XCD-pinned batches. 32 outstanding gathers/wave.
__global__ __launch_bounds__(256, 4) void gather_kernel(
    const unsigned* __restrict__ y1p,        // (B,N,32) bf16-pairs
    const unsigned* __restrict__ y2p,
    const int* __restrict__ ei,              // (B, N, 16)
    const float* __restrict__ gamma,
    unsigned* __restrict__ hselp,            // (B,N,32) bf16-pairs
    float* __restrict__ statsN)              // (32,128)
{
    const int tid  = threadIdx.x;
    const int w    = __builtin_amdgcn_readfirstlane(tid >> 6);
    const int lane = tid & 63;
    const int half = lane >> 5;
    const int c2   = lane & 31;
    const int g    = blockIdx.x;
    const int xcd  = g & 7;
    const int b    = xcd >> 1;
    const int row0 = b * NDIM + (xcd & 1) * 8192 + (g >> 3) * 32 + w * 8;

    const unsigned sgn0 = (gamma[2 * c2]     >= 0.0f) ? 0x80000000u : 0u;
    const unsigned sgn1 = (gamma[2 * c2 + 1] >= 0.0f) ? 0x80000000u : 0u;
    const unsigned* y2b = y2p + ((size_t)b * NDIM) * 32 + c2;

    float ssum0 = 0.f, ssum1 = 0.f, ssq0 = 0.f, ssq1 = 0.f;

    for (int rp = 0; rp < 8; rp += 4) {
        const int ra = row0 + rp;            // pair0: rows ra, ra+1
        const int rb = ra + 2;               // pair1: rows rb, rb+1
        const int* iA = ei + (size_t)ra * KNB;        // wave-uniform -> s_load
        const int* iB = ei + (size_t)(ra + 1) * KNB;
        const int* iC = ei + (size_t)rb * KNB;
        const int* iD = ei + (size_t)(rb + 1) * KNB;

        unsigned u0[KNB], u1[KNB];
        #pragma unroll
        for (int k = 0; k < KNB; ++k) {
            int j = half ? iB[k] : iA[k];
            u0[k] = y2b[(size_t)j * 32];
        }
        #pragma unroll
        for (int k = 0; k < KNB; ++k) {
            int j = half ? iD[k] : iC[k];
            u1[k] = y2b[(size_t)j * 32];
        }
        const unsigned y1u0 = y1p[(size_t)(ra + half) * 32 + c2];
        const unsigned y1u1 = y1p[(size_t)(rb + half) * 32 + c2];

        #pragma unroll 2
        for (int p = 0; p < 2; ++p) {
            const unsigned* u = (p == 0) ? u0 : u1;
            const unsigned y1u = (p == 0) ? y1u0 : y1u1;
            const int rw = ((p == 0) ? ra : rb) + half;

            float s20 = 0.f, s21 = 0.f, q20 = 0.f, q21 = 0.f;
            float M0 = -3.402823e38f, M1 = -3.402823e38f;
            #pragma unroll
            for (int k = 0; k < KNB; k += 2) {
                unsigned lo0 = u[k] << 16,     hi0 = u[k] & 0xffff0000u;
                unsigned lo1 = u[k + 1] << 16, hi1 = u[k + 1] & 0xffff0000u;
                float v00 = __uint_as_float(lo0), v01 = __uint_as_float(hi0);
                float v10 = __uint_as_float(lo1), v11 = __uint_as_float(hi1);
                s20 += v00;               s21 += v01;
                q20 = fmaf(v00, v00, q20); q21 = fmaf(v01, v01, q21);
                s20 += v10;               s21 += v11;
                q20 = fmaf(v10, v10, q20); q21 = fmaf(v11, v11, q21);
                // paired -> v_max3_f32 (max is order-independent: bit-identical)
                M0 = fmaxf(fmaxf(M0, __uint_as_float(lo0 ^ sgn0)),
                           __uint_as_float(lo1 ^ sgn0));
                M1 = fmaxf(fmaxf(M1, __uint_as_float(hi0 ^ sgn1)),
                           __uint_as_float(hi1 ^ sgn1));
            }
            const float y1lo = __uint_as_float(y1u << 16);
            const float y1hi = __uint_as_float(y1u & 0xffff0000u);
            const float h0 = y1lo - __uint_as_float(__float_as_uint(M0) ^ sgn0);
            const float h1 = y1hi - __uint_as_float(__float_as_uint(M1) ^ sgn1);
            hselp[(size_t)rw * 32 + c2] = pack_bf16(h0, h1);
            ssum0 += 16.f * y1lo - s20;
            ssum1 += 16.f * y1hi - s21;
            ssq0  += fmaf(fmaf(-2.f, s20, 16.f * y1lo), y1lo, q20);
            ssq1  += fmaf(fmaf(-2.f, s21, 16.f * y1hi), y1hi, q21);
        }
    }

    __shared__ float rs[8][64];
    __shared__ float rq[8][64];
    rs[w * 2 + half][c2 * 2]     = ssum0;
    rs[w * 2 + half][c2 * 2 + 1] = ssum1;
    rq[w * 2 + half][c2 * 2]     = ssq0;
    rq[w * 2 + half][c2 * 2 + 1] = ssq1;
    __syncthreads();
    if (tid < 128) {
        const int c = tid & 63;
        float v = 0.f;
        if (tid < 64) { for (int r = 0; r < 8; ++r) v += rs[r][c]; }
        else          { for (int r = 0; r < 8; ++r) v += rq[r][c]; }
        atomicAdd(&statsN[(g & 31) * 128 + tid], v);   // striped: ~64 adds/line
    }
}

// ---------------- Kernel 3: reduce-in-prologue + affine + leaky + transpose ----------------
__global__ __launch_bounds__(256) void out_kernel(
    const unsigned* __restrict__ hselp,      // (B,N,32) bf16-pairs
    const float* __restrict__ statsN,        // (32,128)
    const float* __restrict__ gamma,
    const float* __restrict__ beta,
    float* __restrict__ out)                 // (B, 64, N)
{
    __shared__ float tile[64 * 65];
    __shared__ float colsum[128];
    __shared__ float sc[64], bi[64];
    const int tid = threadIdx.x;

    if (tid < 128) {
        float v = 0.f;
        #pragma unroll
        for (int i = 0; i < 32; ++i) v += statsN[i * 128 + tid];
        colsum[tid] = v;
    }
    __syncthreads();
    if (tid < 64) {
        float mean = colsum[tid] * (1.0f / BNK_F);
        float var  = colsum[64 + tid] * (1.0f / BNK_F) - mean * mean;
        float s    = gamma[tid] * rsqrtf(var + 1e-5f);
        sc[tid] = s;
        bi[tid] = beta[tid] - mean * s;
    }
    __syncthreads();

    const int b  = blockIdx.x >> 8;
    const int n0 = (blockIdx.x & 255) << 6;
    const size_t bn0 = (size_t)b * NDIM + n0;
    const int c4 = tid & 15;

    for (int r = tid >> 4; r < 64; r += 16) {
        uint2 u = *(const uint2*)&hselp[(bn0 + r) * 32 + c4 * 2];
        float v0 = fmaf(sc[4 * c4],     __uint_as_float(u.x << 16),         bi[4 * c4]);
        float v1 = fmaf(sc[4 * c4 + 1], __uint_as_float(u.x & 0xffff0000u), bi[4 * c4 + 1]);
        float v2 = fmaf(sc[4 * c4 + 2], __uint_as_float(u.y << 16),         bi[4 * c4 + 2]);
        float v3 = fmaf(sc[4 * c4 + 3], __uint_as_float(u.y & 0xffff0000u), bi[4 * c4 + 3]);
        v0 = (v0 >= 0.f) ? v0 : 0.2f * v0;
        v1 = (v1 >= 0.f) ? v1 : 0.2f * v1;
        v2 = (v2 >= 0.f) ? v2 : 0.2f * v2;
        v3 = (v3 >= 0.f) ? v3 : 0.2f * v3;
        tile[r * 65 + 4 * c4]     = v0;
        tile[r * 65 + 4 * c4 + 1] = v1;
        tile[r * 65 + 4 * c4 + 2] = v2;
        tile[r * 65 + 4 * c4 + 3] = v3;
    }
    __syncthreads();
    const int lane = tid & 63;
    for (int o = tid >> 6; o < 64; o += 4)
        out[((size_t)(b * 64 + o) << 14) + n0 + lane] = tile[lane * 65 + o];
}

extern "C" void kernel_launch(void* const* d_in, const int* in_sizes, int n_in,
                              void* d_out, int out_size, void* d_ws, size_t ws_size,
                              hipStream_t stream) {
    const float* x     = (const float*)d_in[0];
    const int*   ei    = (const int*)d_in[1];
    const float* W     = (const float*)d_in[2];
    const float* gamma = (const float*)d_in[3];
    const float* beta  = (const float*)d_in[4];
    float* out = (float*)d_out;

    char* ws = (char*)d_ws;
    unsigned* y1p    = (unsigned*)(ws);                       // 8 MiB (bf16 pairs)
    unsigned* y2p    = (unsigned*)(ws + 8388608);             // 8 MiB
    unsigned* hselp  = (unsigned*)(ws + 16777216);            // 8 MiB
    float*    statsN = (float*)(ws + 25165824);               // 16 KiB (32x128)

    gemm_mfma_kernel <<<dim3(1024), dim3(256), 0, stream>>>(x, W, y1p, y2p, statsN);
    gather_kernel    <<<dim3(2048), dim3(256), 0, stream>>>(y1p, y2p, ei, gamma, hselp, statsN);
    out_kernel       <<<dim3(1024), dim3(256), 0, stream>>>(hselp, statsN, gamma, beta, out);
}

// Round 3
// 103.978 us; speedup vs baseline: 1.1836x; 1.0180x over previous
//
#include <hip/hip_runtime.h>
#include <hip/hip_bf16.h>
#include <stdint.h>

// B=4, C=64, N=16384, K=16, CO=64 (fp32 I/O, int32 idx)
// R3 = R2 + (k2 SADDR 32-bit gather offsets) + (k3 dwordx4 stores):
//  k1 gemm (MFMA): A-staging via float4 W loads (unchanged from R2)
//  k2 gather: R0 burst structure, addressing rewritten to uniform-base +
//             32-bit voffset (v_lshl_add_u32 + saddr load), max3-paired extremes
//  k3 out: affine loop unchanged; store side reads 4 stride-65 LDS vals ->
//          one global_store_dwordx4 (VMEM stores 16 -> 4 per thread)
#define NDIM 16384
#define KNB 16
#define BNK_F 1048576.0f

typedef __attribute__((ext_vector_type(8))) short bf16x8_t;
typedef __attribute__((ext_vector_type(4))) float f32x4_t;

__device__ inline unsigned pack_bf16(float a, float b) {
    return (unsigned)__bfloat16_as_ushort(__float2bfloat16(a))
         | ((unsigned)__bfloat16_as_ushort(__float2bfloat16(b)) << 16);
}

// ---------------- Kernel 1: MFMA GEMM (R2-proven, unchanged) ----------------
__global__ __launch_bounds__(256) void gemm_mfma_kernel(
    const float* __restrict__ x,            // (B, 64, N)
    const float* __restrict__ W,            // (64, 128)
    unsigned* __restrict__ y1p,             // (B,N,32) bf16-pairs
    unsigned* __restrict__ y2p,             // (B,N,32) bf16-pairs
    float* __restrict__ statsN)             // (32,128) striped stats - zeroed here
{
    __shared__ alignas(16) short lds_a[128 * 72];  // row pad 72 -> 2-way-free b128
    __shared__ alignas(16) short lds_b[64 * 72];   // x tile, n-major

    const int tid = threadIdx.x;
    if (blockIdx.x == 0) {
        for (int i = tid; i < 4096; i += 256) statsN[i] = 0.0f;
    }
    const int b  = blockIdx.x >> 8;
    const int n0 = (blockIdx.x & 255) << 6;

    // stage A (bf16) via float4: 1024 (row r, float4-col q) pairs.
    for (int idx = tid; idx < 1024; idx += 256) {
        const int r = idx >> 4, q = idx & 15;
        const f32x4_t wa = *(const f32x4_t*)&W[r * 128 + q * 4];
        const f32x4_t wb = *(const f32x4_t*)&W[r * 128 + 64 + q * 4];
        uint2 pa = { pack_bf16(wa[0] + wb[0], wa[1] + wb[1]),
                     pack_bf16(wa[2] + wb[2], wa[3] + wb[3]) };
        uint2 pb = { pack_bf16(wb[0], wb[1]), pack_bf16(wb[2], wb[3]) };
        *(uint2*)&lds_a[r * 72 + q * 4]        = pa;
        *(uint2*)&lds_a[(64 + r) * 72 + q * 4] = pb;
    }
    // stage B: x (c-major fp32) -> lds_b[n][c] bf16, packed-pair writes
    {
        const float* xb = x + (size_t)b * 64 * NDIM + n0;
        const int n = tid & 63;
        unsigned* lb32 = (unsigned*)lds_b;
        for (int cp = tid >> 6; cp < 32; cp += 4) {
            int c = cp * 2;
            float x0 = xb[(size_t)c * NDIM + n];
            float x1 = xb[(size_t)(c + 1) * NDIM + n];
            lb32[n * 36 + cp] = pack_bf16(x0, x1);
        }
    }
    __syncthreads();

    const int lane = tid & 63;
    const int w    = tid >> 6;
    const int m    = lane & 15;              // A-row (ch) AND B-col (n) lane index
    const int q    = lane >> 4;              // k-octet / D-row quad
    const int n    = w * 16 + m;

    const bf16x8_t b0 = *(const bf16x8_t*)&lds_b[n * 72 + q * 8];        // k 0..31
    const bf16x8_t b1 = *(const bf16x8_t*)&lds_b[n * 72 + q * 8 + 32];   // k 32..63

    const size_t rowbase = ((size_t)(b * NDIM + n0 + n)) * 32;
    #pragma unroll
    for (int t = 0; t < 8; ++t) {
        const short* ap = &lds_a[(t * 16 + m) * 72 + q * 8];
        bf16x8_t a0 = *(const bf16x8_t*)ap;
        bf16x8_t a1 = *(const bf16x8_t*)(ap + 32);
        f32x4_t acc = {0.f, 0.f, 0.f, 0.f};
        acc = __builtin_amdgcn_mfma_f32_16x16x32_bf16(a0, b0, acc, 0, 0, 0);
        acc = __builtin_amdgcn_mfma_f32_16x16x32_bf16(a1, b1, acc, 0, 0, 0);
        unsigned* dst = (t < 4) ? y1p : y2p;
        uint2 pk = { pack_bf16(acc[0], acc[1]), pack_bf16(acc[2], acc[3]) };
        *(uint2*)&dst[rowbase + (t & 3) * 8 + q * 2] = pk;
    }
}

// ---------------- Kernel 2: gather, 2 interleaved row-pairs, SADDR offsets ----------------
// 2048 blocks x 256, XCD-pinned batches. 32 outstanding gathers/wave.
__global__ __launch_bounds__(256, 4) void gather_kernel(
    const unsigned* __restrict__ y1p,        // (B,N,32) bf16-pairs
    const unsigned* __restrict__ y2p,
    const int* __restrict__ ei,              // (B, N, 16)
    const float* __restrict__ gamma,
    unsigned* __restrict__ hselp,            // (B,N,32) bf16-pairs
    float* __restrict__ statsN)              // (32,128)
{
    const int tid  = threadIdx.x;
    const int w    = __builtin_amdgcn_readfirstlane(tid >> 6);
    const int lane = tid & 63;
    const int half = lane >> 5;
    const int c2   = lane & 31;
    const int g    = blockIdx.x;
    const int xcd  = g & 7;
    const int b    = xcd >> 1;
    const int row0 = b * NDIM + (xcd & 1) * 8192 + (g >> 3) * 32 + w * 8;

    const unsigned sgn0 = (gamma[2 * c2]     >= 0.0f) ? 0x80000000u : 0u;
    const unsigned sgn1 = (gamma[2 * c2 + 1] >= 0.0f) ? 0x80000000u : 0u;
    // uniform scalar base + 32-bit unsigned per-lane byte offset -> saddr loads
    const char* y2base = (const char*)y2p + (size_t)b * NDIM * 128;
    const unsigned coff = (unsigned)(c2 << 2);

    float ssum0 = 0.f, ssum1 = 0.f, ssq0 = 0.f, ssq1 = 0.f;

    for (int rp = 0; rp < 8; rp += 4) {
        const int ra = row0 + rp;            // pair0: rows ra, ra+1
        const int rb = ra + 2;               // pair1: rows rb, rb+1
        const int* iA = ei + (size_t)ra * KNB;        // wave-uniform -> s_load
        const int* iB = ei + (size_t)(ra + 1) * KNB;
        const int* iC = ei + (size_t)rb * KNB;
        const int* iD = ei + (size_t)(rb + 1) * KNB;

        unsigned u0[KNB], u1[KNB];
        #pragma unroll
        for (int k = 0; k < KNB; ++k) {
            int j = half ? iB[k] : iA[k];
            u0[k] = *(const unsigned*)(y2base + ((((unsigned)j) << 7) + coff));
        }
        #pragma unroll
        for (int k = 0; k < KNB; ++k) {
            int j = half ? iD[k] : iC[k];
            u1[k] = *(const unsigned*)(y2base + ((((unsigned)j) << 7) + coff));
        }
        const unsigned y1u0 = y1p[(size_t)(ra + half) * 32 + c2];
        const unsigned y1u1 = y1p[(size_t)(rb + half) * 32 + c2];

        #pragma unroll 2
        for (int p = 0; p < 2; ++p) {
            const unsigned* u = (p == 0) ? u0 : u1;
            const unsigned y1u = (p == 0) ? y1u0 : y1u1;
            const int rw = ((p == 0) ? ra : rb) + half;

            float s20 = 0.f, s21 = 0.f, q20 = 0.f, q21 = 0.f;
            float M0 = -3.402823e38f, M1 = -3.402823e38f;
            #pragma unroll
            for (int k = 0; k < KNB; k += 2) {
                unsigned lo0 = u[k] << 16,     hi0 = u[k] & 0xffff0000u;
                unsigned lo1 = u[k + 1] << 16, hi1 = u[k + 1] & 0xffff0000u;
                float v00 = __uint_as_float(lo0), v01 = __uint_as_float(hi0);
                float v10 = __uint_as_float(lo1), v11 = __uint_as_float(hi1);
                s20 += v00;                s21 += v01;
                q20 = fmaf(v00, v00, q20); q21 = fmaf(v01, v01, q21);
                s20 += v10;                s21 += v11;
                q20 = fmaf(v10, v10, q20); q21 = fmaf(v11, v11, q21);
                // paired -> v_max3_f32 (max is order-independent: bit-identical)
                M0 = fmaxf(fmaxf(M0, __uint_as_float(lo0 ^ sgn0)),
                           __uint_as_float(lo1 ^ sgn0));
                M1 = fmaxf(fmaxf(M1, __uint_as_float(hi0 ^ sgn1)),
                           __uint_as_float(hi1 ^ sgn1));
            }
            const float y1lo = __uint_as_float(y1u << 16);
            const float y1hi = __uint_as_float(y1u & 0xffff0000u);
            const float h0 = y1lo - __uint_as_float(__float_as_uint(M0) ^ sgn0);
            const float h1 = y1hi - __uint_as_float(__float_as_uint(M1) ^ sgn1);
            hselp[(size_t)rw * 32 + c2] = pack_bf16(h0, h1);
            ssum0 += 16.f * y1lo - s20;
            ssum1 += 16.f * y1hi - s21;
            ssq0  += fmaf(fmaf(-2.f, s20, 16.f * y1lo), y1lo, q20);
            ssq1  += fmaf(fmaf(-2.f, s21, 16.f * y1hi), y1hi, q21);
        }
    }

    __shared__ float rs[8][64];
    __shared__ float rq[8][64];
    rs[w * 2 + half][c2 * 2]     = ssum0;
    rs[w * 2 + half][c2 * 2 + 1] = ssum1;
    rq[w * 2 + half][c2 * 2]     = ssq0;
    rq[w * 2 + half][c2 * 2 + 1] = ssq1;
    __syncthreads();
    if (tid < 128) {
        const int c = tid & 63;
        float v = 0.f;
        if (tid < 64) { for (int r = 0; r < 8; ++r) v += rs[r][c]; }
        else          { for (int r = 0; r < 8; ++r) v += rq[r][c]; }
        atomicAdd(&statsN[(g & 31) * 128 + tid], v);   // striped: ~64 adds/line
    }
}

// ---------------- Kernel 3: reduce-in-prologue + affine + leaky + transpose ----------------
__global__ __launch_bounds__(256) void out_kernel(
    const unsigned* __restrict__ hselp,      // (B,N,32) bf16-pairs
    const float* __restrict__ statsN,        // (32,128)
    const float* __restrict__ gamma,
    const float* __restrict__ beta,
    float* __restrict__ out)                 // (B, 64, N)
{
    __shared__ float tile[64 * 65];
    __shared__ float colsum[128];
    __shared__ float sc[64], bi[64];
    const int tid = threadIdx.x;

    if (tid < 128) {
        float v = 0.f;
        #pragma unroll
        for (int i = 0; i < 32; ++i) v += statsN[i * 128 + tid];
        colsum[tid] = v;
    }
    __syncthreads();
    if (tid < 64) {
        float mean = colsum[tid] * (1.0f / BNK_F);
        float var  = colsum[64 + tid] * (1.0f / BNK_F) - mean * mean;
        float s    = gamma[tid] * rsqrtf(var + 1e-5f);
        sc[tid] = s;
        bi[tid] = beta[tid] - mean * s;
    }
    __syncthreads();

    const int b  = blockIdx.x >> 8;
    const int n0 = (blockIdx.x & 255) << 6;
    const size_t bn0 = (size_t)b * NDIM + n0;
    const int c4 = tid & 15;

    for (int r = tid >> 4; r < 64; r += 16) {
        uint2 u = *(const uint2*)&hselp[(bn0 + r) * 32 + c4 * 2];
        float v0 = fmaf(sc[4 * c4],     __uint_as_float(u.x << 16),         bi[4 * c4]);
        float v1 = fmaf(sc[4 * c4 + 1], __uint_as_float(u.x & 0xffff0000u), bi[4 * c4 + 1]);
        float v2 = fmaf(sc[4 * c4 + 2], __uint_as_float(u.y << 16),         bi[4 * c4 + 2]);
        float v3 = fmaf(sc[4 * c4 + 3], __uint_as_float(u.y & 0xffff0000u), bi[4 * c4 + 3]);
        v0 = (v0 >= 0.f) ? v0 : 0.2f * v0;
        v1 = (v1 >= 0.f) ? v1 : 0.2f * v1;
        v2 = (v2 >= 0.f) ? v2 : 0.2f * v2;
        v3 = (v3 >= 0.f) ? v3 : 0.2f * v3;
        tile[r * 65 + 4 * c4]     = v0;
        tile[r * 65 + 4 * c4 + 1] = v1;
        tile[r * 65 + 4 * c4 + 2] = v2;
        tile[r * 65 + 4 * c4 + 3] = v3;
    }
    __syncthreads();
    // store: each thread gathers 4 consecutive n from the stride-65 tile
    // (banks (4*ln + i + o) mod 32 -> 2-way, free) and stores one dwordx4.
    const int ln = tid & 15;
    for (int o = tid >> 4; o < 64; o += 16) {
        f32x4_t v;
        v[0] = tile[(ln * 4 + 0) * 65 + o];
        v[1] = tile[(ln * 4 + 1) * 65 + o];
        v[2] = tile[(ln * 4 + 2) * 65 + o];
        v[3] = tile[(ln * 4 + 3) * 65 + o];
        *(f32x4_t*)&out[((size_t)(b * 64 + o) << 14) + n0 + ln * 4] = v;
    }
}

extern "C" void kernel_launch(void* const* d_in, const int* in_sizes, int n_in,
                              void* d_out, int out_size, void* d_ws, size_t ws_size,
                              hipStream_t stream) {
    const float* x     = (const float*)d_in[0];
    const int*   ei    = (const int*)d_in[1];
    const float* W     = (const float*)d_in[2];
    const float* gamma = (const float*)d_in[3];
    const float* beta  = (const float*)d_in[4];
    float* out = (float*)d_out;

    char* ws = (char*)d_ws;
    unsigned* y1p    = (unsigned*)(ws);                       // 8 MiB (bf16 pairs)
    unsigned* y2p    = (unsigned*)(ws + 8388608);             // 8 MiB
    unsigned* hselp  = (unsigned*)(ws + 16777216);            // 8 MiB
    float*    statsN = (float*)(ws + 25165824);               // 16 KiB (32x128)

    gemm_mfma_kernel <<<dim3(1024), dim3(256), 0, stream>>>(x, W, y1p, y2p, statsN);
    gather_kernel    <<<dim3(2048), dim3(256), 0, stream>>>(y1p, y2p, ei, gamma, hselp, statsN);
    out_kernel       <<<dim3(1024), dim3(256), 0, stream>>>(hselp, statsN, gamma, beta, out);
}